// Round 8
// baseline (788.654 us; speedup 1.0000x reference)
//
#include <hip/hip_runtime.h>
#include <stdint.h>

#define NSCENE 16
#define NPED 32
#define NB_TOT 512
#define HD 64
#define ED 64
#define D1 8192
#define BOTN 1024

typedef unsigned short ushort_t;
typedef __attribute__((ext_vector_type(4))) float f32x4;
typedef __attribute__((ext_vector_type(8))) __bf16 bf16x8;  // gfx950 mfma operand (V8y)
typedef __attribute__((ext_vector_type(4))) unsigned int u32x4;
typedef __attribute__((ext_vector_type(2))) unsigned int u32x2;

union frag_u { u32x4 u; bf16x8 v; };

__device__ __forceinline__ float bf2f(ushort_t u) {
  union { unsigned int i; float f; } x;
  x.i = ((unsigned int)u) << 16;
  return x.f;
}

__device__ __forceinline__ ushort_t f2bf(float f) {
  union { float f; unsigned int i; } x;
  x.f = f;
  unsigned int u = x.i + 0x7fffu + ((x.i >> 16) & 1u);
  return (ushort_t)(u >> 16);
}

// pack two f32 -> two bf16 RNE (lo in bits [15:0])
__device__ __forceinline__ unsigned int packbf(float lo, float hi) {
#if __has_builtin(__builtin_amdgcn_cvt_pk_bf16_f32)
  typedef __attribute__((ext_vector_type(2))) __bf16 bf16x2_t;
  union { bf16x2_t v; unsigned int u; } x;
  x.v = __builtin_amdgcn_cvt_pk_bf16_f32(lo, hi);
  return x.u;
#else
  return (unsigned int)f2bf(lo) | ((unsigned int)f2bf(hi) << 16);
#endif
}

// unpack u32 holding 2 bf16 -> 2 f32 (2 VALU ops)
__device__ __forceinline__ void unpk(unsigned int u, float& lo, float& hi) {
  union { unsigned int i; float f; } a, b;
  a.i = u << 16;
  b.i = u & 0xffff0000u;
  lo = a.f;
  hi = b.f;
}

__device__ __forceinline__ float clip1(float x) {
  return fminf(fmaxf(x, -1.f), 1.f);
}

// ---------------------------------------------------------------------------
// k_detect: decide whether float inputs are fp32 (expected) or bf16.
// Also produce canonical fp32 copies of end_pos and b2.
// ---------------------------------------------------------------------------
__global__ __launch_bounds__(256) void k_detect(
    const void* __restrict__ W1v, const void* __restrict__ end_posv,
    const void* __restrict__ b2v, int* __restrict__ flag,
    float* __restrict__ epf, float* __restrict__ b2f) {
  __shared__ int cnt[256];
  __shared__ int isbf_s;
  const int t = threadIdx.x;
  const ushort_t* wu = (const ushort_t*)W1v;
  unsigned int u = wu[2 * t];
  int e = (u >> 7) & 0xff;
  cnt[t] = (e >= 90 && e <= 140) ? 1 : 0;
  __syncthreads();
  for (int ofs = 128; ofs > 0; ofs >>= 1) {
    if (t < ofs) cnt[t] += cnt[t + ofs];
    __syncthreads();
  }
  if (t == 0) {
    isbf_s = (cnt[0] >= 128) ? 1 : 0;
    *flag = isbf_s;
  }
  __syncthreads();
  const int isbf = isbf_s;
  const ushort_t* epu = (const ushort_t*)end_posv;
  const float* epff = (const float*)end_posv;
  const ushort_t* b2u = (const ushort_t*)b2v;
  const float* b2ff = (const float*)b2v;
  for (int i = t; i < 1024; i += 256) {
    epf[i] = isbf ? bf2f(epu[i]) : epff[i];
    b2f[i] = isbf ? bf2f(b2u[i]) : b2ff[i];
  }
}

// ---------------------------------------------------------------------------
// k_prep: M0[k] = sum_e Wsp[0][e]*W1[e][k]; M1 likewise;
//         hbias[k] = b1[k] + sum_e bsp[e]*W1[e][k]
// ---------------------------------------------------------------------------
__global__ __launch_bounds__(256) void k_prep(
    const void* __restrict__ W_spv, const void* __restrict__ b_spv,
    const void* __restrict__ W1v, const void* __restrict__ b1v,
    const int* __restrict__ flag,
    float* __restrict__ M0, float* __restrict__ M1, float* __restrict__ hbias) {
  const int isbf = *flag;
  const ushort_t* Wspu = (const ushort_t*)W_spv;
  const float* Wspf = (const float*)W_spv;
  const ushort_t* bspu = (const ushort_t*)b_spv;
  const float* bspf = (const float*)b_spv;
  const ushort_t* W1u = (const ushort_t*)W1v;
  const float* W1f = (const float*)W1v;
  const ushort_t* b1u = (const ushort_t*)b1v;
  const float* b1f = (const float*)b1v;
  int k = blockIdx.x * 256 + threadIdx.x;
  float m0 = 0.f, m1 = 0.f, hb = 0.f;
  for (int e = 0; e < ED; ++e) {
    float w = isbf ? bf2f(W1u[e * D1 + k]) : W1f[e * D1 + k];
    float s0 = isbf ? bf2f(Wspu[e]) : Wspf[e];
    float s1 = isbf ? bf2f(Wspu[ED + e]) : Wspf[ED + e];
    float bs = isbf ? bf2f(bspu[e]) : bspf[e];
    m0 += s0 * w;
    m1 += s1 * w;
    hb += bs * w;
  }
  M0[k] = m0;
  M1[k] = m1;
  hbias[k] = hb + (isbf ? bf2f(b1u[k]) : b1f[k]);
}

// ---------------------------------------------------------------------------
// k_hc v2: hc[j][k] = hbias[k] + sum_h h[j][hh]*W1[64+hh][k]  (bf16 out)
// grid (8 kt, 32 jt), 256 thr: block = 16 j-rows x 1024 k; thread = 16j x 4k.
// ---------------------------------------------------------------------------
__global__ __launch_bounds__(256) void k_hc(
    const void* __restrict__ hv_, const void* __restrict__ W1v,
    const float* __restrict__ hbias, const int* __restrict__ flag,
    ushort_t* __restrict__ hcb) {
  const int isbf = *flag;
  const int kb = blockIdx.x;  // 0..7
  const int jt = blockIdx.y;  // 0..31
  const int t = threadIdx.x;
  const int kbase = kb * 1024 + t * 4;
  float acc[16][4];
#pragma unroll
  for (int j = 0; j < 16; ++j)
#pragma unroll
    for (int c = 0; c < 4; ++c) acc[j][c] = 0.f;

  if (isbf) {
    const ushort_t* wp = (const ushort_t*)W1v + (size_t)ED * D1 + kbase;
    const ushort_t* hp = (const ushort_t*)hv_ + jt * 16 * HD;
    for (int hh = 0; hh < HD; ++hh) {
      u32x2 wv = *(const u32x2*)(wp + (size_t)hh * D1);
      float w0 = bf2f((ushort_t)(wv.x & 0xffffu)), w1 = bf2f((ushort_t)(wv.x >> 16));
      float w2 = bf2f((ushort_t)(wv.y & 0xffffu)), w3 = bf2f((ushort_t)(wv.y >> 16));
#pragma unroll
      for (int j = 0; j < 16; ++j) {
        float hj = bf2f(hp[j * HD + hh]);
        acc[j][0] += hj * w0;
        acc[j][1] += hj * w1;
        acc[j][2] += hj * w2;
        acc[j][3] += hj * w3;
      }
    }
  } else {
    const float* wp = (const float*)W1v + (size_t)ED * D1 + kbase;
    const float* hp = (const float*)hv_ + jt * 16 * HD;
#pragma unroll 4
    for (int hh = 0; hh < HD; ++hh) {
      float4 w = *(const float4*)(wp + (size_t)hh * D1);
#pragma unroll
      for (int j = 0; j < 16; ++j) {
        float hj = hp[j * HD + hh];
        acc[j][0] += hj * w.x;
        acc[j][1] += hj * w.y;
        acc[j][2] += hj * w.z;
        acc[j][3] += hj * w.w;
      }
    }
  }
  float4 hb = *(const float4*)(hbias + kbase);
#pragma unroll
  for (int j = 0; j < 16; ++j) {
    u32x2 pk;
    pk.x = packbf(acc[j][0] + hb.x, acc[j][1] + hb.y);
    pk.y = packbf(acc[j][2] + hb.z, acc[j][3] + hb.w);
    *(u32x2*)(hcb + (size_t)(jt * 16 + j) * D1 + kbase) = pk;
  }
}

// ---------------------------------------------------------------------------
// k_tr: W2T[n][k] = (bf16)W2[k][n]   (8192x1024 -> 1024x8192)
// ---------------------------------------------------------------------------
__global__ __launch_bounds__(256) void k_tr(const void* __restrict__ W2v,
                                            const int* __restrict__ flag,
                                            ushort_t* __restrict__ W2T) {
  __shared__ ushort_t tile[64][72];
  const int isbf = *flag;
  int kt = blockIdx.x, nt = blockIdx.y;
  int t = threadIdx.x;
  int r = t >> 3, c8 = (t & 7) * 8;
#pragma unroll
  for (int i = 0; i < 2; ++i) {
    int row = i * 32 + r;
    size_t base = (size_t)(kt * 64 + row) * BOTN + nt * 64 + c8;
    if (isbf) {
      u32x4 v = *(const u32x4*)((const ushort_t*)W2v + base);
      *(u32x4*)&tile[row][c8] = v;
    } else {
      const float* src = (const float*)W2v + base;
      float4 w0 = *(const float4*)src;
      float4 w1 = *(const float4*)(src + 4);
      u32x4 pk;
      pk.x = packbf(w0.x, w0.y);
      pk.y = packbf(w0.z, w0.w);
      pk.z = packbf(w1.x, w1.y);
      pk.w = packbf(w1.z, w1.w);
      *(u32x4*)&tile[row][c8] = pk;
    }
  }
  __syncthreads();
#pragma unroll
  for (int i = 0; i < 2; ++i) {
    int nrow = i * 32 + r;
    union { ushort_t us[8]; u32x4 v; } pk;
#pragma unroll
    for (int jj = 0; jj < 8; ++jj) pk.us[jj] = tile[c8 + jj][nrow];
    *(u32x4*)(W2T + (size_t)(nt * 64 + nrow) * D1 + kt * 64 + c8) = pk.v;
  }
}

// ---------------------------------------------------------------------------
// k_gemm v4: barrier-free, LDS-free, all-register K-loop.
// BM=64 BN=512 BK=64; grid 512: nb=bid&1, mb=bid>>1 (0..255).
// 4 waves, each 64m x 128n (acc 4x8 f32x4 = 128 regs).
// A fragments generated per-lane from hc (+ r0*M0 + r1*M1, relu) directly in
// A-operand layout: af[mt] row = rl + mt*16 -> (g=mt>>1? no: see map) uses
// hc row b=rl (mt 0,2) / rl+16 (mt 1,3), r-values per mt.
// B fragments loaded global->VGPR per (ki,nt): W2T[row][k0+ki*32+q*8..+8].
// No __syncthreads in the K-loop: compiler emits fine-grained vmcnt between
// loads and MFMA (AITER-style interleave).
// ---------------------------------------------------------------------------
__global__ __launch_bounds__(256, 2) void k_gemm(
    const ushort_t* __restrict__ hcb, const float* __restrict__ M0f,
    const float* __restrict__ M1f, const ushort_t* __restrict__ W2T,
    const float* __restrict__ epf, const float* __restrict__ b2f,
    const int* __restrict__ flag, void* __restrict__ outv) {
  const int t = threadIdx.x;
  const int w = t >> 6;
  const int lane = t & 63;
  const int nb = blockIdx.x & 1;
  const int mb = blockIdx.x >> 1;  // 0..255
  const int s = mb >> 4;
  const int abase = (mb & 15) * 2;
  const int isbf = *flag;

  const int rl = lane & 15, q = lane >> 4;

  // r-values per mt: mt0:(g0,b=rl) mt1:(g0,b=rl+16) mt2:(g1,b=rl) mt3:(g1,b=rl+16)
  float r0v[4], r1v[4];
  {
    int pa0 = (s * 32 + abase) * 2, pa1 = pa0 + 2;
    int pbA = (s * 32 + rl) * 2, pbB = pbA + 32;
    float ax0 = epf[pa0], ay0 = epf[pa0 + 1];
    float ax1 = epf[pa1], ay1 = epf[pa1 + 1];
    float bxA = epf[pbA], byA = epf[pbA + 1];
    float bxB = epf[pbB], byB = epf[pbB + 1];
    r0v[0] = clip1(bxA - ax0); r1v[0] = clip1(byA - ay0);
    r0v[1] = clip1(bxB - ax0); r1v[1] = clip1(byB - ay0);
    r0v[2] = clip1(bxA - ax1); r1v[2] = clip1(byA - ay1);
    r0v[3] = clip1(bxB - ax1); r1v[3] = clip1(byB - ay1);
  }

  const ushort_t* hcA = hcb + (size_t)(s * 32 + rl) * D1 + q * 8;  // b=rl
  const ushort_t* hcB = hcA + 16 * D1;                             // b=rl+16
  const float* M0p = M0f + q * 8;
  const float* M1p = M1f + q * 8;
  const ushort_t* Bbase = W2T + (size_t)(nb * 512 + w * 128 + rl) * D1 + q * 8;

  f32x4 acc[4][8];
#pragma unroll
  for (int mt = 0; mt < 4; ++mt)
#pragma unroll
    for (int nt = 0; nt < 8; ++nt) acc[mt][nt] = (f32x4){0.f, 0.f, 0.f, 0.f};

  for (int kk = 0; kk < D1 / 64; ++kk) {
    const int k0 = kk * 64;
#pragma unroll
    for (int ki = 0; ki < 2; ++ki) {
      const int ko = k0 + ki * 32;
      // ---- B fragments: direct global->VGPR ----
      frag_u bfr[8];
#pragma unroll
      for (int nt = 0; nt < 8; ++nt)
        bfr[nt].u = *(const u32x4*)(Bbase + (size_t)nt * 16 * D1 + ko);
      // ---- hc + M chunks ----
      u32x4 hAu = *(const u32x4*)(hcA + ko);
      u32x4 hBu = *(const u32x4*)(hcB + ko);
      f32x4 m0a = *(const f32x4*)(M0p + ko);
      f32x4 m0b = *(const f32x4*)(M0p + ko + 4);
      f32x4 m1a = *(const f32x4*)(M1p + ko);
      f32x4 m1b = *(const f32x4*)(M1p + ko + 4);
      float ha[8], hb[8];
      unpk(hAu.x, ha[0], ha[1]); unpk(hAu.y, ha[2], ha[3]);
      unpk(hAu.z, ha[4], ha[5]); unpk(hAu.w, ha[6], ha[7]);
      unpk(hBu.x, hb[0], hb[1]); unpk(hBu.y, hb[2], hb[3]);
      unpk(hBu.z, hb[4], hb[5]); unpk(hBu.w, hb[6], hb[7]);
      // ---- A fragments: relu(h + r0*M0 + r1*M1), packed bf16 ----
      frag_u af[4];
#pragma unroll
      for (int mt = 0; mt < 4; ++mt) {
        const float* hp = (mt & 1) ? hb : ha;
        float r0 = r0v[mt], r1 = r1v[mt];
        float v0 = fmaxf(hp[0] + r0 * m0a.x + r1 * m1a.x, 0.f);
        float v1 = fmaxf(hp[1] + r0 * m0a.y + r1 * m1a.y, 0.f);
        float v2 = fmaxf(hp[2] + r0 * m0a.z + r1 * m1a.z, 0.f);
        float v3 = fmaxf(hp[3] + r0 * m0a.w + r1 * m1a.w, 0.f);
        float v4 = fmaxf(hp[4] + r0 * m0b.x + r1 * m1b.x, 0.f);
        float v5 = fmaxf(hp[5] + r0 * m0b.y + r1 * m1b.y, 0.f);
        float v6 = fmaxf(hp[6] + r0 * m0b.z + r1 * m1b.z, 0.f);
        float v7 = fmaxf(hp[7] + r0 * m0b.w + r1 * m1b.w, 0.f);
        af[mt].u.x = packbf(v0, v1);
        af[mt].u.y = packbf(v2, v3);
        af[mt].u.z = packbf(v4, v5);
        af[mt].u.w = packbf(v6, v7);
      }
      // ---- MFMA 4x8 ----
#pragma unroll
      for (int mt = 0; mt < 4; ++mt)
#pragma unroll
        for (int nt = 0; nt < 8; ++nt)
          acc[mt][nt] = __builtin_amdgcn_mfma_f32_16x16x32_bf16(
              af[mt].v, bfr[nt].v, acc[mt][nt], 0, 0, 0);
    }
  }

  // ---- epilogue: max over b (32 m-rows/group), +b2, relu, store ----
#pragma unroll
  for (int g = 0; g < 2; ++g) {
    int orow = s * 32 + abase + g;
#pragma unroll
    for (int nt = 0; nt < 8; ++nt) {
      f32x4 x0 = acc[2 * g][nt], x1 = acc[2 * g + 1][nt];
      float v = fmaxf(fmaxf(fmaxf(x0.x, x0.y), fmaxf(x0.z, x0.w)),
                      fmaxf(fmaxf(x1.x, x1.y), fmaxf(x1.z, x1.w)));
      v = fmaxf(v, __shfl_xor(v, 16, 64));
      v = fmaxf(v, __shfl_xor(v, 32, 64));
      if (lane < 16) {
        int col = nb * 512 + w * 128 + nt * 16 + lane;
        float o = fmaxf(v + b2f[col], 0.f);
        if (isbf)
          ((ushort_t*)outv)[(size_t)orow * BOTN + col] = f2bf(o);
        else
          ((float*)outv)[(size_t)orow * BOTN + col] = o;
      }
    }
  }
}

extern "C" void kernel_launch(void* const* d_in, const int* in_sizes, int n_in,
                              void* d_out, int out_size, void* d_ws, size_t ws_size,
                              hipStream_t stream) {
  (void)in_sizes; (void)n_in; (void)out_size; (void)ws_size;
  const void* h_states = d_in[0];
  const void* end_pos = d_in[1];
  // d_in[2] rel_pos: unused by reference; d_in[3] seq_start_end: fixed equal scenes
  const void* W_sp = d_in[4];
  const void* b_sp = d_in[5];
  const void* W1 = d_in[6];
  const void* b1 = d_in[7];
  const void* W2 = d_in[8];
  const void* b2 = d_in[9];

  char* ws = (char*)d_ws;
  ushort_t* hcb = (ushort_t*)ws;                         // 8 MB  (512x8192 bf16)
  ushort_t* W2T = (ushort_t*)(ws + (8u << 20));          // 16 MB (1024x8192 bf16)
  float* M0f = (float*)(ws + (24u << 20));               // 32 KB
  float* M1f = (float*)(ws + (24u << 20) + 32768);       // 32 KB
  float* hbias = (float*)(ws + (24u << 20) + 65536);     // 32 KB
  float* epf = (float*)(ws + (24u << 20) + 98304);       // 4 KB
  float* b2f = (float*)(ws + (24u << 20) + 102400);      // 4 KB
  int* flag = (int*)(ws + (24u << 20) + 106496);         // 4 B

  k_detect<<<dim3(1), dim3(256), 0, stream>>>(W1, end_pos, b2, flag, epf, b2f);
  k_prep<<<dim3(32), dim3(256), 0, stream>>>(W_sp, b_sp, W1, b1, flag, M0f, M1f, hbias);
  k_hc<<<dim3(8, 32), dim3(256), 0, stream>>>(h_states, W1, hbias, flag, hcb);
  k_tr<<<dim3(128, 16), dim3(256), 0, stream>>>(W2, flag, W2T);
  k_gemm<<<dim3(512), dim3(256), 0, stream>>>(hcb, M0f, M1f, W2T, epf, b2f, flag, d_out);
}

// Round 9
// 783.618 us; speedup vs baseline: 1.0064x; 1.0064x over previous
//
#include <hip/hip_runtime.h>
#include <stdint.h>

#define NSCENE 16
#define NPED 32
#define NB_TOT 512
#define HD 64
#define ED 64
#define D1 8192
#define BOTN 1024

typedef unsigned short ushort_t;
typedef __attribute__((ext_vector_type(4))) float f32x4;
typedef __attribute__((ext_vector_type(8))) __bf16 bf16x8;  // gfx950 mfma operand (V8y)
typedef __attribute__((ext_vector_type(4))) unsigned int u32x4;
typedef __attribute__((ext_vector_type(2))) unsigned int u32x2;

union frag_u { u32x4 u; bf16x8 v; };

__device__ __forceinline__ float bf2f(ushort_t u) {
  union { unsigned int i; float f; } x;
  x.i = ((unsigned int)u) << 16;
  return x.f;
}

__device__ __forceinline__ ushort_t f2bf(float f) {
  union { float f; unsigned int i; } x;
  x.f = f;
  unsigned int u = x.i + 0x7fffu + ((x.i >> 16) & 1u);
  return (ushort_t)(u >> 16);
}

// pack two f32 -> two bf16 RNE (lo in bits [15:0])
__device__ __forceinline__ unsigned int packbf(float lo, float hi) {
#if __has_builtin(__builtin_amdgcn_cvt_pk_bf16_f32)
  typedef __attribute__((ext_vector_type(2))) __bf16 bf16x2_t;
  union { bf16x2_t v; unsigned int u; } x;
  x.v = __builtin_amdgcn_cvt_pk_bf16_f32(lo, hi);
  return x.u;
#else
  return (unsigned int)f2bf(lo) | ((unsigned int)f2bf(hi) << 16);
#endif
}

// unpack u32 holding 2 bf16 -> 2 f32
__device__ __forceinline__ void unpk(unsigned int u, float& lo, float& hi) {
  union { unsigned int i; float f; } a, b;
  a.i = u << 16;
  b.i = u & 0xffff0000u;
  lo = a.f;
  hi = b.f;
}

__device__ __forceinline__ float clip1(float x) {
  return fminf(fmaxf(x, -1.f), 1.f);
}

// ---------------------------------------------------------------------------
// k_detect: fp32-vs-bf16 input sniff + canonical fp32 copies of end_pos/b2.
// ---------------------------------------------------------------------------
__global__ __launch_bounds__(256) void k_detect(
    const void* __restrict__ W1v, const void* __restrict__ end_posv,
    const void* __restrict__ b2v, int* __restrict__ flag,
    float* __restrict__ epf, float* __restrict__ b2f) {
  __shared__ int cnt[256];
  __shared__ int isbf_s;
  const int t = threadIdx.x;
  const ushort_t* wu = (const ushort_t*)W1v;
  unsigned int u = wu[2 * t];
  int e = (u >> 7) & 0xff;
  cnt[t] = (e >= 90 && e <= 140) ? 1 : 0;
  __syncthreads();
  for (int ofs = 128; ofs > 0; ofs >>= 1) {
    if (t < ofs) cnt[t] += cnt[t + ofs];
    __syncthreads();
  }
  if (t == 0) {
    isbf_s = (cnt[0] >= 128) ? 1 : 0;
    *flag = isbf_s;
  }
  __syncthreads();
  const int isbf = isbf_s;
  const ushort_t* epu = (const ushort_t*)end_posv;
  const float* epff = (const float*)end_posv;
  const ushort_t* b2u = (const ushort_t*)b2v;
  const float* b2ff = (const float*)b2v;
  for (int i = t; i < 1024; i += 256) {
    epf[i] = isbf ? bf2f(epu[i]) : epff[i];
    b2f[i] = isbf ? bf2f(b2u[i]) : b2ff[i];
  }
}

// ---------------------------------------------------------------------------
// k_prep: M0/M1 = W_sp rows folded through W1[:64]; hbias = b1 + b_sp@W1[:64]
// ---------------------------------------------------------------------------
__global__ __launch_bounds__(256) void k_prep(
    const void* __restrict__ W_spv, const void* __restrict__ b_spv,
    const void* __restrict__ W1v, const void* __restrict__ b1v,
    const int* __restrict__ flag,
    float* __restrict__ M0, float* __restrict__ M1, float* __restrict__ hbias) {
  const int isbf = *flag;
  const ushort_t* Wspu = (const ushort_t*)W_spv;
  const float* Wspf = (const float*)W_spv;
  const ushort_t* bspu = (const ushort_t*)b_spv;
  const float* bspf = (const float*)b_spv;
  const ushort_t* W1u = (const ushort_t*)W1v;
  const float* W1f = (const float*)W1v;
  const ushort_t* b1u = (const ushort_t*)b1v;
  const float* b1f = (const float*)b1v;
  int k = blockIdx.x * 256 + threadIdx.x;
  float m0 = 0.f, m1 = 0.f, hb = 0.f;
  for (int e = 0; e < ED; ++e) {
    float w = isbf ? bf2f(W1u[e * D1 + k]) : W1f[e * D1 + k];
    float s0 = isbf ? bf2f(Wspu[e]) : Wspf[e];
    float s1 = isbf ? bf2f(Wspu[ED + e]) : Wspf[ED + e];
    float bs = isbf ? bf2f(bspu[e]) : bspf[e];
    m0 += s0 * w;
    m1 += s1 * w;
    hb += bs * w;
  }
  M0[k] = m0;
  M1[k] = m1;
  hbias[k] = hb + (isbf ? bf2f(b1u[k]) : b1f[k]);
}

// ---------------------------------------------------------------------------
// k_hc v2: hc[j][k] = hbias[k] + sum_h h[j][hh]*W1[64+hh][k]  (bf16 out)
// grid (8 kt, 32 jt), 256 thr: block = 16 j-rows x 1024 k; thread = 16j x 4k.
// ---------------------------------------------------------------------------
__global__ __launch_bounds__(256) void k_hc(
    const void* __restrict__ hv_, const void* __restrict__ W1v,
    const float* __restrict__ hbias, const int* __restrict__ flag,
    ushort_t* __restrict__ hcb) {
  const int isbf = *flag;
  const int kb = blockIdx.x;  // 0..7
  const int jt = blockIdx.y;  // 0..31
  const int t = threadIdx.x;
  const int kbase = kb * 1024 + t * 4;
  float acc[16][4];
#pragma unroll
  for (int j = 0; j < 16; ++j)
#pragma unroll
    for (int c = 0; c < 4; ++c) acc[j][c] = 0.f;

  if (isbf) {
    const ushort_t* wp = (const ushort_t*)W1v + (size_t)ED * D1 + kbase;
    const ushort_t* hp = (const ushort_t*)hv_ + jt * 16 * HD;
    for (int hh = 0; hh < HD; ++hh) {
      u32x2 wv = *(const u32x2*)(wp + (size_t)hh * D1);
      float w0 = bf2f((ushort_t)(wv.x & 0xffffu)), w1 = bf2f((ushort_t)(wv.x >> 16));
      float w2 = bf2f((ushort_t)(wv.y & 0xffffu)), w3 = bf2f((ushort_t)(wv.y >> 16));
#pragma unroll
      for (int j = 0; j < 16; ++j) {
        float hj = bf2f(hp[j * HD + hh]);
        acc[j][0] += hj * w0;
        acc[j][1] += hj * w1;
        acc[j][2] += hj * w2;
        acc[j][3] += hj * w3;
      }
    }
  } else {
    const float* wp = (const float*)W1v + (size_t)ED * D1 + kbase;
    const float* hp = (const float*)hv_ + jt * 16 * HD;
#pragma unroll 4
    for (int hh = 0; hh < HD; ++hh) {
      float4 w = *(const float4*)(wp + (size_t)hh * D1);
#pragma unroll
      for (int j = 0; j < 16; ++j) {
        float hj = hp[j * HD + hh];
        acc[j][0] += hj * w.x;
        acc[j][1] += hj * w.y;
        acc[j][2] += hj * w.z;
        acc[j][3] += hj * w.w;
      }
    }
  }
  float4 hb = *(const float4*)(hbias + kbase);
#pragma unroll
  for (int j = 0; j < 16; ++j) {
    u32x2 pk;
    pk.x = packbf(acc[j][0] + hb.x, acc[j][1] + hb.y);
    pk.y = packbf(acc[j][2] + hb.z, acc[j][3] + hb.w);
    *(u32x2*)(hcb + (size_t)(jt * 16 + j) * D1 + kbase) = pk;
  }
}

// ---------------------------------------------------------------------------
// k_tr: W2T[n][k] = (bf16)W2[k][n]   (8192x1024 -> 1024x8192)
// ---------------------------------------------------------------------------
__global__ __launch_bounds__(256) void k_tr(const void* __restrict__ W2v,
                                            const int* __restrict__ flag,
                                            ushort_t* __restrict__ W2T) {
  __shared__ ushort_t tile[64][72];
  const int isbf = *flag;
  int kt = blockIdx.x, nt = blockIdx.y;
  int t = threadIdx.x;
  int r = t >> 3, c8 = (t & 7) * 8;
#pragma unroll
  for (int i = 0; i < 2; ++i) {
    int row = i * 32 + r;
    size_t base = (size_t)(kt * 64 + row) * BOTN + nt * 64 + c8;
    if (isbf) {
      u32x4 v = *(const u32x4*)((const ushort_t*)W2v + base);
      *(u32x4*)&tile[row][c8] = v;
    } else {
      const float* src = (const float*)W2v + base;
      float4 w0 = *(const float4*)src;
      float4 w1 = *(const float4*)(src + 4);
      u32x4 pk;
      pk.x = packbf(w0.x, w0.y);
      pk.y = packbf(w0.z, w0.w);
      pk.z = packbf(w1.x, w1.y);
      pk.w = packbf(w1.z, w1.w);
      *(u32x4*)&tile[row][c8] = pk;
    }
  }
  __syncthreads();
#pragma unroll
  for (int i = 0; i < 2; ++i) {
    int nrow = i * 32 + r;
    union { ushort_t us[8]; u32x4 v; } pk;
#pragma unroll
    for (int jj = 0; jj < 8; ++jj) pk.us[jj] = tile[c8 + jj][nrow];
    *(u32x4*)(W2T + (size_t)(nt * 64 + nrow) * D1 + kt * 64 + c8) = pk.v;
  }
}

// ---------------------------------------------------------------------------
// k_gemm v5: barrier-free all-register K-loop + explicit 1-stage pipeline.
// BM=64 BN=512; grid 512: nb=bid&1, mb=bid>>1. 4 waves, each 64m x 128n.
// Stage = 32 k-elements (256 stages). During stage s: issue ALL stage-s+1
// loads (B frags + hc + M) into the alternate register set, then compute
// stage s from registers loaded a full stage ago (~600 cyc cover vs ~200 cyc
// L2 latency). Fixes R8's vmcnt-drain serialization (B loads were older than
// hc loads in the queue, so waiting for hc drained everything).
// ---------------------------------------------------------------------------
__global__ __launch_bounds__(256, 2) void k_gemm(
    const ushort_t* __restrict__ hcb, const float* __restrict__ M0f,
    const float* __restrict__ M1f, const ushort_t* __restrict__ W2T,
    const float* __restrict__ epf, const float* __restrict__ b2f,
    const int* __restrict__ flag, void* __restrict__ outv) {
  const int t = threadIdx.x;
  const int w = t >> 6;
  const int lane = t & 63;
  const int nb = blockIdx.x & 1;
  const int mb = blockIdx.x >> 1;  // 0..255
  const int s = mb >> 4;
  const int abase = (mb & 15) * 2;
  const int isbf = *flag;

  const int rl = lane & 15, q = lane >> 4;

  // r-values per mt: mt0:(a0,b=rl) mt1:(a0,b=rl+16) mt2:(a1,b=rl) mt3:(a1,b=rl+16)
  float r0v[4], r1v[4];
  {
    int pa0 = (s * 32 + abase) * 2, pa1 = pa0 + 2;
    int pbA = (s * 32 + rl) * 2, pbB = pbA + 32;
    float ax0 = epf[pa0], ay0 = epf[pa0 + 1];
    float ax1 = epf[pa1], ay1 = epf[pa1 + 1];
    float bxA = epf[pbA], byA = epf[pbA + 1];
    float bxB = epf[pbB], byB = epf[pbB + 1];
    r0v[0] = clip1(bxA - ax0); r1v[0] = clip1(byA - ay0);
    r0v[1] = clip1(bxB - ax0); r1v[1] = clip1(byB - ay0);
    r0v[2] = clip1(bxA - ax1); r1v[2] = clip1(byA - ay1);
    r0v[3] = clip1(bxB - ax1); r1v[3] = clip1(byB - ay1);
  }

  const ushort_t* hcA = hcb + (size_t)(s * 32 + rl) * D1 + q * 8;  // b=rl
  const ushort_t* hcB = hcA + 16 * D1;                             // b=rl+16
  const float* M0p = M0f + q * 8;
  const float* M1p = M1f + q * 8;
  const ushort_t* Bbase = W2T + (size_t)(nb * 512 + w * 128 + rl) * D1 + q * 8;

  f32x4 acc[4][8];
#pragma unroll
  for (int mt = 0; mt < 4; ++mt)
#pragma unroll
    for (int nt = 0; nt < 8; ++nt) acc[mt][nt] = (f32x4){0.f, 0.f, 0.f, 0.f};

  // double-buffered stage registers
  frag_u bfr[2][8];
  u32x4 hAu[2], hBu[2];
  f32x4 m0a[2], m0b[2], m1a[2], m1b[2];

#define LOAD_STAGE(buf, stg)                                                   \
  do {                                                                         \
    const int ko_ = (stg) * 32;                                                \
    hAu[buf] = *(const u32x4*)(hcA + ko_);                                     \
    hBu[buf] = *(const u32x4*)(hcB + ko_);                                     \
    m0a[buf] = *(const f32x4*)(M0p + ko_);                                     \
    m0b[buf] = *(const f32x4*)(M0p + ko_ + 4);                                 \
    m1a[buf] = *(const f32x4*)(M1p + ko_);                                     \
    m1b[buf] = *(const f32x4*)(M1p + ko_ + 4);                                 \
    _Pragma("unroll") for (int nt_ = 0; nt_ < 8; ++nt_)                        \
        bfr[buf][nt_].u = *(const u32x4*)(Bbase + (size_t)nt_ * 16 * D1 + ko_);\
  } while (0)

  LOAD_STAGE(0, 0);

#pragma unroll 2
  for (int stg = 0; stg < 256; ++stg) {
    const int cur = stg & 1, nxt = cur ^ 1;
    const int pf = (stg < 255) ? (stg + 1) : 255;  // last prefetch redundant
    LOAD_STAGE(nxt, pf);

    // ---- A fragments for stage `cur` (data loaded a full stage ago) ----
    float ha[8], hb[8];
    unpk(hAu[cur].x, ha[0], ha[1]); unpk(hAu[cur].y, ha[2], ha[3]);
    unpk(hAu[cur].z, ha[4], ha[5]); unpk(hAu[cur].w, ha[6], ha[7]);
    unpk(hBu[cur].x, hb[0], hb[1]); unpk(hBu[cur].y, hb[2], hb[3]);
    unpk(hBu[cur].z, hb[4], hb[5]); unpk(hBu[cur].w, hb[6], hb[7]);
    f32x4 ca = m0a[cur], cb = m0b[cur], da = m1a[cur], db = m1b[cur];
    frag_u af[4];
#pragma unroll
    for (int mt = 0; mt < 4; ++mt) {
      const float* hp = (mt & 1) ? hb : ha;
      float r0 = r0v[mt], r1 = r1v[mt];
      float v0 = fmaxf(hp[0] + r0 * ca.x + r1 * da.x, 0.f);
      float v1 = fmaxf(hp[1] + r0 * ca.y + r1 * da.y, 0.f);
      float v2 = fmaxf(hp[2] + r0 * ca.z + r1 * da.z, 0.f);
      float v3 = fmaxf(hp[3] + r0 * ca.w + r1 * da.w, 0.f);
      float v4 = fmaxf(hp[4] + r0 * cb.x + r1 * db.x, 0.f);
      float v5 = fmaxf(hp[5] + r0 * cb.y + r1 * db.y, 0.f);
      float v6 = fmaxf(hp[6] + r0 * cb.z + r1 * db.z, 0.f);
      float v7 = fmaxf(hp[7] + r0 * cb.w + r1 * db.w, 0.f);
      af[mt].u.x = packbf(v0, v1);
      af[mt].u.y = packbf(v2, v3);
      af[mt].u.z = packbf(v4, v5);
      af[mt].u.w = packbf(v6, v7);
    }
    // ---- MFMA 4x8 with stage `cur` B fragments ----
#pragma unroll
    for (int mt = 0; mt < 4; ++mt)
#pragma unroll
      for (int nt = 0; nt < 8; ++nt)
        acc[mt][nt] = __builtin_amdgcn_mfma_f32_16x16x32_bf16(
            af[mt].v, bfr[cur][nt].v, acc[mt][nt], 0, 0, 0);
  }
#undef LOAD_STAGE

  // ---- epilogue: max over b (32 m-rows/group), +b2, relu, store ----
#pragma unroll
  for (int g = 0; g < 2; ++g) {
    int orow = s * 32 + abase + g;
#pragma unroll
    for (int nt = 0; nt < 8; ++nt) {
      f32x4 x0 = acc[2 * g][nt], x1 = acc[2 * g + 1][nt];
      float v = fmaxf(fmaxf(fmaxf(x0.x, x0.y), fmaxf(x0.z, x0.w)),
                      fmaxf(fmaxf(x1.x, x1.y), fmaxf(x1.z, x1.w)));
      v = fmaxf(v, __shfl_xor(v, 16, 64));
      v = fmaxf(v, __shfl_xor(v, 32, 64));
      if (lane < 16) {
        int col = nb * 512 + w * 128 + nt * 16 + lane;
        float o = fmaxf(v + b2f[col], 0.f);
        if (isbf)
          ((ushort_t*)outv)[(size_t)orow * BOTN + col] = f2bf(o);
        else
          ((float*)outv)[(size_t)orow * BOTN + col] = o;
      }
    }
  }
}

extern "C" void kernel_launch(void* const* d_in, const int* in_sizes, int n_in,
                              void* d_out, int out_size, void* d_ws, size_t ws_size,
                              hipStream_t stream) {
  (void)in_sizes; (void)n_in; (void)out_size; (void)ws_size;
  const void* h_states = d_in[0];
  const void* end_pos = d_in[1];
  // d_in[2] rel_pos: unused by reference; d_in[3] seq_start_end: fixed equal scenes
  const void* W_sp = d_in[4];
  const void* b_sp = d_in[5];
  const void* W1 = d_in[6];
  const void* b1 = d_in[7];
  const void* W2 = d_in[8];
  const void* b2 = d_in[9];

  char* ws = (char*)d_ws;
  ushort_t* hcb = (ushort_t*)ws;                         // 8 MB  (512x8192 bf16)
  ushort_t* W2T = (ushort_t*)(ws + (8u << 20));          // 16 MB (1024x8192 bf16)
  float* M0f = (float*)(ws + (24u << 20));               // 32 KB
  float* M1f = (float*)(ws + (24u << 20) + 32768);       // 32 KB
  float* hbias = (float*)(ws + (24u << 20) + 65536);     // 32 KB
  float* epf = (float*)(ws + (24u << 20) + 98304);       // 4 KB
  float* b2f = (float*)(ws + (24u << 20) + 102400);      // 4 KB
  int* flag = (int*)(ws + (24u << 20) + 106496);         // 4 B

  k_detect<<<dim3(1), dim3(256), 0, stream>>>(W1, end_pos, b2, flag, epf, b2f);
  k_prep<<<dim3(32), dim3(256), 0, stream>>>(W_sp, b_sp, W1, b1, flag, M0f, M1f, hbias);
  k_hc<<<dim3(8, 32), dim3(256), 0, stream>>>(h_states, W1, hbias, flag, hcb);
  k_tr<<<dim3(128, 16), dim3(256), 0, stream>>>(W2, flag, W2T);
  k_gemm<<<dim3(512), dim3(256), 0, stream>>>(hcb, M0f, M1f, W2T, epf, b2f, flag, d_out);
}

// Round 10
// 562.412 us; speedup vs baseline: 1.4023x; 1.3933x over previous
//
#include <hip/hip_runtime.h>
#include <stdint.h>

#define NSCENE 16
#define NPED 32
#define NB_TOT 512
#define HD 64
#define ED 64
#define D1 8192
#define BOTN 1024
#define ASTR 36  // A-tile LDS row stride in shorts (72B) for BK=32

typedef unsigned short ushort_t;
typedef __attribute__((ext_vector_type(4))) float f32x4;
typedef __attribute__((ext_vector_type(8))) __bf16 bf16x8;  // gfx950 mfma operand (V8y)
typedef __attribute__((ext_vector_type(4))) unsigned int u32x4;
typedef __attribute__((ext_vector_type(2))) unsigned int u32x2;

union frag_u { u32x4 u; bf16x8 v; };

__device__ __forceinline__ float bf2f(ushort_t u) {
  union { unsigned int i; float f; } x;
  x.i = ((unsigned int)u) << 16;
  return x.f;
}

__device__ __forceinline__ ushort_t f2bf(float f) {
  union { float f; unsigned int i; } x;
  x.f = f;
  unsigned int u = x.i + 0x7fffu + ((x.i >> 16) & 1u);
  return (ushort_t)(u >> 16);
}

// pack two f32 -> two bf16 RNE (lo in bits [15:0])
__device__ __forceinline__ unsigned int packbf(float lo, float hi) {
#if __has_builtin(__builtin_amdgcn_cvt_pk_bf16_f32)
  typedef __attribute__((ext_vector_type(2))) __bf16 bf16x2_t;
  union { bf16x2_t v; unsigned int u; } x;
  x.v = __builtin_amdgcn_cvt_pk_bf16_f32(lo, hi);
  return x.u;
#else
  return (unsigned int)f2bf(lo) | ((unsigned int)f2bf(hi) << 16);
#endif
}

// unpack u32 holding 2 bf16 -> 2 f32
__device__ __forceinline__ void unpk(unsigned int u, float& lo, float& hi) {
  union { unsigned int i; float f; } a, b;
  a.i = u << 16;
  b.i = u & 0xffff0000u;
  lo = a.f;
  hi = b.f;
}

__device__ __forceinline__ float clip1(float x) {
  return fminf(fmaxf(x, -1.f), 1.f);
}

// async global->LDS DMA, 16B/lane; casts through integers (legal reinterpret).
// HW: LDS dest = wave-uniform base + lane*16 — caller arranges that.
__device__ __forceinline__ void async_load16(const void* g, void* l) {
  __builtin_amdgcn_global_load_lds(
      (const __attribute__((address_space(1))) unsigned int*)(unsigned long long)g,
      (__attribute__((address_space(3))) unsigned int*)(unsigned int)(unsigned long long)l,
      16, 0, 0);
}

// ---------------------------------------------------------------------------
// k_detect: fp32-vs-bf16 input sniff + canonical fp32 copies of end_pos/b2.
// ---------------------------------------------------------------------------
__global__ __launch_bounds__(256) void k_detect(
    const void* __restrict__ W1v, const void* __restrict__ end_posv,
    const void* __restrict__ b2v, int* __restrict__ flag,
    float* __restrict__ epf, float* __restrict__ b2f) {
  __shared__ int cnt[256];
  __shared__ int isbf_s;
  const int t = threadIdx.x;
  const ushort_t* wu = (const ushort_t*)W1v;
  unsigned int u = wu[2 * t];
  int e = (u >> 7) & 0xff;
  cnt[t] = (e >= 90 && e <= 140) ? 1 : 0;
  __syncthreads();
  for (int ofs = 128; ofs > 0; ofs >>= 1) {
    if (t < ofs) cnt[t] += cnt[t + ofs];
    __syncthreads();
  }
  if (t == 0) {
    isbf_s = (cnt[0] >= 128) ? 1 : 0;
    *flag = isbf_s;
  }
  __syncthreads();
  const int isbf = isbf_s;
  const ushort_t* epu = (const ushort_t*)end_posv;
  const float* epff = (const float*)end_posv;
  const ushort_t* b2u = (const ushort_t*)b2v;
  const float* b2ff = (const float*)b2v;
  for (int i = t; i < 1024; i += 256) {
    epf[i] = isbf ? bf2f(epu[i]) : epff[i];
    b2f[i] = isbf ? bf2f(b2u[i]) : b2ff[i];
  }
}

// ---------------------------------------------------------------------------
// k_prep: M0/M1 = W_sp rows folded through W1[:64]; hbias = b1 + b_sp@W1[:64]
// ---------------------------------------------------------------------------
__global__ __launch_bounds__(256) void k_prep(
    const void* __restrict__ W_spv, const void* __restrict__ b_spv,
    const void* __restrict__ W1v, const void* __restrict__ b1v,
    const int* __restrict__ flag,
    float* __restrict__ M0, float* __restrict__ M1, float* __restrict__ hbias) {
  const int isbf = *flag;
  const ushort_t* Wspu = (const ushort_t*)W_spv;
  const float* Wspf = (const float*)W_spv;
  const ushort_t* bspu = (const ushort_t*)b_spv;
  const float* bspf = (const float*)b_spv;
  const ushort_t* W1u = (const ushort_t*)W1v;
  const float* W1f = (const float*)W1v;
  const ushort_t* b1u = (const ushort_t*)b1v;
  const float* b1f = (const float*)b1v;
  int k = blockIdx.x * 256 + threadIdx.x;
  float m0 = 0.f, m1 = 0.f, hb = 0.f;
  for (int e = 0; e < ED; ++e) {
    float w = isbf ? bf2f(W1u[e * D1 + k]) : W1f[e * D1 + k];
    float s0 = isbf ? bf2f(Wspu[e]) : Wspf[e];
    float s1 = isbf ? bf2f(Wspu[ED + e]) : Wspf[ED + e];
    float bs = isbf ? bf2f(bspu[e]) : bspf[e];
    m0 += s0 * w;
    m1 += s1 * w;
    hb += bs * w;
  }
  M0[k] = m0;
  M1[k] = m1;
  hbias[k] = hb + (isbf ? bf2f(b1u[k]) : b1f[k]);
}

// ---------------------------------------------------------------------------
// k_hc v2: hc[j][k] = hbias[k] + sum_h h[j][hh]*W1[64+hh][k]  (bf16 out)
// grid (8 kt, 32 jt), 256 thr: block = 16 j-rows x 1024 k; thread = 16j x 4k.
// ---------------------------------------------------------------------------
__global__ __launch_bounds__(256) void k_hc(
    const void* __restrict__ hv_, const void* __restrict__ W1v,
    const float* __restrict__ hbias, const int* __restrict__ flag,
    ushort_t* __restrict__ hcb) {
  const int isbf = *flag;
  const int kb = blockIdx.x;  // 0..7
  const int jt = blockIdx.y;  // 0..31
  const int t = threadIdx.x;
  const int kbase = kb * 1024 + t * 4;
  float acc[16][4];
#pragma unroll
  for (int j = 0; j < 16; ++j)
#pragma unroll
    for (int c = 0; c < 4; ++c) acc[j][c] = 0.f;

  if (isbf) {
    const ushort_t* wp = (const ushort_t*)W1v + (size_t)ED * D1 + kbase;
    const ushort_t* hp = (const ushort_t*)hv_ + jt * 16 * HD;
    for (int hh = 0; hh < HD; ++hh) {
      u32x2 wv = *(const u32x2*)(wp + (size_t)hh * D1);
      float w0 = bf2f((ushort_t)(wv.x & 0xffffu)), w1 = bf2f((ushort_t)(wv.x >> 16));
      float w2 = bf2f((ushort_t)(wv.y & 0xffffu)), w3 = bf2f((ushort_t)(wv.y >> 16));
#pragma unroll
      for (int j = 0; j < 16; ++j) {
        float hj = bf2f(hp[j * HD + hh]);
        acc[j][0] += hj * w0;
        acc[j][1] += hj * w1;
        acc[j][2] += hj * w2;
        acc[j][3] += hj * w3;
      }
    }
  } else {
    const float* wp = (const float*)W1v + (size_t)ED * D1 + kbase;
    const float* hp = (const float*)hv_ + jt * 16 * HD;
#pragma unroll 4
    for (int hh = 0; hh < HD; ++hh) {
      float4 w = *(const float4*)(wp + (size_t)hh * D1);
#pragma unroll
      for (int j = 0; j < 16; ++j) {
        float hj = hp[j * HD + hh];
        acc[j][0] += hj * w.x;
        acc[j][1] += hj * w.y;
        acc[j][2] += hj * w.z;
        acc[j][3] += hj * w.w;
      }
    }
  }
  float4 hb = *(const float4*)(hbias + kbase);
#pragma unroll
  for (int j = 0; j < 16; ++j) {
    u32x2 pk;
    pk.x = packbf(acc[j][0] + hb.x, acc[j][1] + hb.y);
    pk.y = packbf(acc[j][2] + hb.z, acc[j][3] + hb.w);
    *(u32x2*)(hcb + (size_t)(jt * 16 + j) * D1 + kbase) = pk;
  }
}

// ---------------------------------------------------------------------------
// k_tr: W2T[n][k] = (bf16)W2[k][n]   (8192x1024 -> 1024x8192)
// ---------------------------------------------------------------------------
__global__ __launch_bounds__(256) void k_tr(const void* __restrict__ W2v,
                                            const int* __restrict__ flag,
                                            ushort_t* __restrict__ W2T) {
  __shared__ ushort_t tile[64][72];
  const int isbf = *flag;
  int kt = blockIdx.x, nt = blockIdx.y;
  int t = threadIdx.x;
  int r = t >> 3, c8 = (t & 7) * 8;
#pragma unroll
  for (int i = 0; i < 2; ++i) {
    int row = i * 32 + r;
    size_t base = (size_t)(kt * 64 + row) * BOTN + nt * 64 + c8;
    if (isbf) {
      u32x4 v = *(const u32x4*)((const ushort_t*)W2v + base);
      *(u32x4*)&tile[row][c8] = v;
    } else {
      const float* src = (const float*)W2v + base;
      float4 w0 = *(const float4*)src;
      float4 w1 = *(const float4*)(src + 4);
      u32x4 pk;
      pk.x = packbf(w0.x, w0.y);
      pk.y = packbf(w0.z, w0.w);
      pk.z = packbf(w1.x, w1.y);
      pk.w = packbf(w1.z, w1.w);
      *(u32x4*)&tile[row][c8] = pk;
    }
  }
  __syncthreads();
#pragma unroll
  for (int i = 0; i < 2; ++i) {
    int nrow = i * 32 + r;
    union { ushort_t us[8]; u32x4 v; } pk;
#pragma unroll
    for (int jj = 0; jj < 8; ++jj) pk.us[jj] = tile[c8 + jj][nrow];
    *(u32x4*)(W2T + (size_t)(nt * 64 + nrow) * D1 + kt * 64 + c8) = pk.v;
  }
}

// ---------------------------------------------------------------------------
// k_gemm v6: LDS double-buffered DMA pipeline, covered barrier drain.
// BM=128 BN=512 BK=32; grid 256 = (M/128=128 mb) x (N/512=2 nb), 1 block/CU.
// 512 threads = 8 waves (2m x 4n), wave tile 64m x 128n, acc 4x8 f32x4.
// Per kk: issue DMA(B, kk+1 -> buf nxt); MFMA(kk) from buf cur (~1240 cyc
// covers the 585-cyc DMA); A-gen(kk+1) -> aLds nxt; ONE barrier. The
// vmcnt(0)-before-barrier is harmless: the DMA had a full MFMA phase.
// A-gen: each thread owns one A row (m=t>>2) and one 8-elem k-chunk (t&3).
// ---------------------------------------------------------------------------
__global__ __launch_bounds__(512, 2) void k_gemm(
    const ushort_t* __restrict__ hcb, const float* __restrict__ M0f,
    const float* __restrict__ M1f, const ushort_t* __restrict__ W2T,
    const float* __restrict__ epf, const float* __restrict__ b2f,
    const int* __restrict__ flag, void* __restrict__ outv) {
  __shared__ ushort_t aLds[2][128 * ASTR];  // 2 x 9 KB
  __shared__ ushort_t bLds[2][512 * 32];    // 2 x 32 KB

  const int t = threadIdx.x;
  const int w = t >> 6;
  const int lane = t & 63;
  const int nb = blockIdx.x & 1;
  const int mb = blockIdx.x >> 1;  // 0..127
  const int s = mb >> 3;
  const int abase = (mb & 7) * 4;
  const int wm = w >> 2, wn = w & 3;
  const int rl = lane & 15, q = lane >> 4;
  const int isbf = *flag;

  // ---- A-gen assignment: thread -> (A row, k-chunk) ----
  const int arow = t >> 2;   // 0..127  (m_local)
  const int kc = t & 3;      // 8-elem chunk within BK=32
  const int gA = arow >> 5;  // 0..3 (wave-uniform)
  const int bA = arow & 31;
  float r0, r1;
  {
    int pa = (s * 32 + abase + gA) * 2;
    int pb = (s * 32 + bA) * 2;
    r0 = clip1(epf[pb] - epf[pa]);
    r1 = clip1(epf[pb + 1] - epf[pa + 1]);
  }
  const ushort_t* hcRow = hcb + (size_t)(s * 32 + bA) * D1 + kc * 8;
  const float* M0p = M0f + kc * 8;
  const float* M1p = M1f + kc * 8;
  ushort_t* aW0 = &aLds[0][arow * ASTR + kc * 8];
  ushort_t* aW1 = &aLds[1][arow * ASTR + kc * 8];

  // ---- B DMA assignment: wave w covers rows w*64 + i*16, lane -> (row,chunk)
  const int drow = w * 64 + (lane >> 2);  // + i*16
  const int dch = lane & 3;
  const ushort_t* bG = W2T + (size_t)(nb * 512 + drow) * D1 + dch * 8;
  // LDS dest offset (shorts): drow*32 + dch*8 = w*2048 + lane*8 (+ i*512)
  ushort_t* bW0 = &bLds[0][w * 2048 + lane * 8];
  ushort_t* bW1 = &bLds[1][w * 2048 + lane * 8];

  // ---- fragment read pointers ----
  const ushort_t* aR0 = &aLds[0][(wm * 64 + rl) * ASTR + q * 8];
  const ushort_t* aR1 = &aLds[1][(wm * 64 + rl) * ASTR + q * 8];
  const ushort_t* bR0 = &bLds[0][(wn * 128 + rl) * 32 + q * 8];
  const ushort_t* bR1 = &bLds[1][(wn * 128 + rl) * 32 + q * 8];

  f32x4 acc[4][8];
#pragma unroll
  for (int mt = 0; mt < 4; ++mt)
#pragma unroll
    for (int nt = 0; nt < 8; ++nt) acc[mt][nt] = (f32x4){0.f, 0.f, 0.f, 0.f};

#define DMA_B(dst, kkv)                                                        \
  do {                                                                         \
    const size_t off_ = (size_t)(kkv) * 32;                                    \
    _Pragma("unroll") for (int i_ = 0; i_ < 4; ++i_)                           \
        async_load16(bG + (size_t)i_ * 16 * D1 + off_, (dst) + i_ * 512);      \
  } while (0)

#define AGEN(dst, kkv)                                                         \
  do {                                                                         \
    const int ko_ = (kkv) * 32;                                                \
    u32x4 hv_ = *(const u32x4*)(hcRow + ko_);                                  \
    f32x4 m0_ = *(const f32x4*)(M0p + ko_);                                    \
    f32x4 m1_ = *(const f32x4*)(M1p + ko_);                                    \
    float h0, h1, h2, h3, h4, h5, h6, h7;                                      \
    unpk(hv_.x, h0, h1); unpk(hv_.y, h2, h3);                                  \
    unpk(hv_.z, h4, h5); unpk(hv_.w, h6, h7);                                  \
    f32x4 m0b_ = *(const f32x4*)(M0p + ko_ + 4);                               \
    f32x4 m1b_ = *(const f32x4*)(M1p + ko_ + 4);                               \
    float v0 = fmaxf(h0 + r0 * m0_.x + r1 * m1_.x, 0.f);                       \
    float v1 = fmaxf(h1 + r0 * m0_.y + r1 * m1_.y, 0.f);                       \
    float v2 = fmaxf(h2 + r0 * m0_.z + r1 * m1_.z, 0.f);                       \
    float v3 = fmaxf(h3 + r0 * m0_.w + r1 * m1_.w, 0.f);                       \
    float v4 = fmaxf(h4 + r0 * m0b_.x + r1 * m1b_.x, 0.f);                     \
    float v5 = fmaxf(h5 + r0 * m0b_.y + r1 * m1b_.y, 0.f);                     \
    float v6 = fmaxf(h6 + r0 * m0b_.z + r1 * m1b_.z, 0.f);                     \
    float v7 = fmaxf(h7 + r0 * m0b_.w + r1 * m1b_.w, 0.f);                     \
    u32x4 pk_;                                                                 \
    pk_.x = packbf(v0, v1);                                                    \
    pk_.y = packbf(v2, v3);                                                    \
    pk_.z = packbf(v4, v5);                                                    \
    pk_.w = packbf(v6, v7);                                                    \
    *(u32x4*)(dst) = pk_;                                                      \
  } while (0)

  // ---- prologue: stage kk=0 into buffer 0 ----
  DMA_B(bW0, 0);
  AGEN(aW0, 0);
  __syncthreads();

  for (int kk = 0; kk < 256; ++kk) {
    const int cur = kk & 1;
    const int kn = (kk < 255) ? (kk + 1) : 255;  // last prefetch redundant
    // ---- prefetch next stage into the other buffer ----
    if (cur == 0) DMA_B(bW1, kn); else DMA_B(bW0, kn);

    // ---- MFMA from current buffer (covers DMA + A-gen latency) ----
    const ushort_t* aR = cur ? aR1 : aR0;
    const ushort_t* bR = cur ? bR1 : bR0;
    bf16x8 af[4], bfr[8];
#pragma unroll
    for (int mt = 0; mt < 4; ++mt)
      af[mt] = *(const bf16x8*)(aR + mt * 16 * ASTR);
#pragma unroll
    for (int nt = 0; nt < 8; ++nt)
      bfr[nt] = *(const bf16x8*)(bR + nt * 16 * 32);
#pragma unroll
    for (int mt = 0; mt < 4; ++mt)
#pragma unroll
      for (int nt = 0; nt < 8; ++nt)
        acc[mt][nt] = __builtin_amdgcn_mfma_f32_16x16x32_bf16(
            af[mt], bfr[nt], acc[mt][nt], 0, 0, 0);

    // ---- A-gen for next stage into the other buffer ----
    if (cur == 0) AGEN(aW1, kn); else AGEN(aW0, kn);

    __syncthreads();
  }
#undef DMA_B
#undef AGEN

  // ---- epilogue: max over b (32 m-rows/group), +b2, relu, store ----
  // C/D layout: n-col = lane&15, m = mt*16 + q*4 + reg (+ wm*64).
#pragma unroll
  for (int gi = 0; gi < 2; ++gi) {
    int g = wm * 2 + gi;
    int orow = s * 32 + abase + g;
#pragma unroll
    for (int nt = 0; nt < 8; ++nt) {
      f32x4 x0 = acc[2 * gi][nt], x1 = acc[2 * gi + 1][nt];
      float v = fmaxf(fmaxf(fmaxf(x0.x, x0.y), fmaxf(x0.z, x0.w)),
                      fmaxf(fmaxf(x1.x, x1.y), fmaxf(x1.z, x1.w)));
      v = fmaxf(v, __shfl_xor(v, 16, 64));
      v = fmaxf(v, __shfl_xor(v, 32, 64));
      if (lane < 16) {
        int col = nb * 512 + wn * 128 + nt * 16 + lane;
        float o = fmaxf(v + b2f[col], 0.f);
        if (isbf)
          ((ushort_t*)outv)[(size_t)orow * BOTN + col] = f2bf(o);
        else
          ((float*)outv)[(size_t)orow * BOTN + col] = o;
      }
    }
  }
}

extern "C" void kernel_launch(void* const* d_in, const int* in_sizes, int n_in,
                              void* d_out, int out_size, void* d_ws, size_t ws_size,
                              hipStream_t stream) {
  (void)in_sizes; (void)n_in; (void)out_size; (void)ws_size;
  const void* h_states = d_in[0];
  const void* end_pos = d_in[1];
  // d_in[2] rel_pos: unused by reference; d_in[3] seq_start_end: fixed equal scenes
  const void* W_sp = d_in[4];
  const void* b_sp = d_in[5];
  const void* W1 = d_in[6];
  const void* b1 = d_in[7];
  const void* W2 = d_in[8];
  const void* b2 = d_in[9];

  char* ws = (char*)d_ws;
  ushort_t* hcb = (ushort_t*)ws;                         // 8 MB  (512x8192 bf16)
  ushort_t* W2T = (ushort_t*)(ws + (8u << 20));          // 16 MB (1024x8192 bf16)
  float* M0f = (float*)(ws + (24u << 20));               // 32 KB
  float* M1f = (float*)(ws + (24u << 20) + 32768);       // 32 KB
  float* hbias = (float*)(ws + (24u << 20) + 65536);     // 32 KB
  float* epf = (float*)(ws + (24u << 20) + 98304);       // 4 KB
  float* b2f = (float*)(ws + (24u << 20) + 102400);      // 4 KB
  int* flag = (int*)(ws + (24u << 20) + 106496);         // 4 B

  k_detect<<<dim3(1), dim3(256), 0, stream>>>(W1, end_pos, b2, flag, epf, b2f);
  k_prep<<<dim3(32), dim3(256), 0, stream>>>(W_sp, b_sp, W1, b1, flag, M0f, M1f, hbias);
  k_hc<<<dim3(8, 32), dim3(256), 0, stream>>>(h_states, W1, hbias, flag, hcb);
  k_tr<<<dim3(128, 16), dim3(256), 0, stream>>>(W2, flag, W2T);
  k_gemm<<<dim3(256), dim3(512), 0, stream>>>(hcb, M0f, M1f, W2T, epf, b2f, flag, d_out);
}

// Round 11
// 410.739 us; speedup vs baseline: 1.9201x; 1.3693x over previous
//
#include <hip/hip_runtime.h>
#include <stdint.h>

#define NSCENE 16
#define NPED 32
#define NB_TOT 512
#define HD 64
#define ED 64
#define D1 8192
#define BOTN 1024

typedef unsigned short ushort_t;
typedef __attribute__((ext_vector_type(4))) float f32x4;
typedef __attribute__((ext_vector_type(8))) __bf16 bf16x8;  // gfx950 mfma operand (V8y)
typedef __attribute__((ext_vector_type(4))) unsigned int u32x4;
typedef __attribute__((ext_vector_type(2))) unsigned int u32x2;

__device__ __forceinline__ float bf2f(ushort_t u) {
  union { unsigned int i; float f; } x;
  x.i = ((unsigned int)u) << 16;
  return x.f;
}

__device__ __forceinline__ ushort_t f2bf(float f) {
  union { float f; unsigned int i; } x;
  x.f = f;
  unsigned int u = x.i + 0x7fffu + ((x.i >> 16) & 1u);
  return (ushort_t)(u >> 16);
}

// pack two f32 -> two bf16 RNE (lo in bits [15:0])
__device__ __forceinline__ unsigned int packbf(float lo, float hi) {
#if __has_builtin(__builtin_amdgcn_cvt_pk_bf16_f32)
  typedef __attribute__((ext_vector_type(2))) __bf16 bf16x2_t;
  union { bf16x2_t v; unsigned int u; } x;
  x.v = __builtin_amdgcn_cvt_pk_bf16_f32(lo, hi);
  return x.u;
#else
  return (unsigned int)f2bf(lo) | ((unsigned int)f2bf(hi) << 16);
#endif
}

// unpack u32 holding 2 bf16 -> 2 f32
__device__ __forceinline__ void unpk(unsigned int u, float& lo, float& hi) {
  union { unsigned int i; float f; } a, b;
  a.i = u << 16;
  b.i = u & 0xffff0000u;
  lo = a.f;
  hi = b.f;
}

__device__ __forceinline__ float clip1(float x) {
  return fminf(fmaxf(x, -1.f), 1.f);
}

// async global->LDS DMA, 16B/lane; casts through integers (legal reinterpret).
// HW: LDS dest = wave-uniform base + lane*16 — caller arranges that.
__device__ __forceinline__ void async_load16(const void* g, void* l) {
  __builtin_amdgcn_global_load_lds(
      (const __attribute__((address_space(1))) unsigned int*)(unsigned long long)g,
      (__attribute__((address_space(3))) unsigned int*)(unsigned int)(unsigned long long)l,
      16, 0, 0);
}

// ---------------------------------------------------------------------------
// k_pre: ALL preprocessing in one kernel of independent blocks.
//   bid <  2048 : W2 transpose tile (64k x 64n)  -> W2T
//   bid <  2304 : hc block (16 j-rows x 1024 k, hbias inline) -> hcb
//   bid <  2336 : M0/M1 fold (256 k each)
//   bid == 2336 : epf/b2f canonicalize + *flag
// Every block detects input dtype inline (1 KB of W1, LDS reduce) — no
// cross-block dependency, no 1-block serializing kernel.
// ---------------------------------------------------------------------------
__global__ __launch_bounds__(256) void k_pre(
    const void* __restrict__ hv_, const void* __restrict__ end_posv,
    const void* __restrict__ W_spv, const void* __restrict__ b_spv,
    const void* __restrict__ W1v, const void* __restrict__ b1v,
    const void* __restrict__ W2v, const void* __restrict__ b2v,
    int* __restrict__ flag, float* __restrict__ epf, float* __restrict__ b2f,
    float* __restrict__ M0, float* __restrict__ M1,
    ushort_t* __restrict__ hcb, ushort_t* __restrict__ W2T) {
  __shared__ ushort_t tile[64][72];
  __shared__ int cnt[256];
  __shared__ int isbf_sh;
  const int t = threadIdx.x;
  const int bid = blockIdx.x;

  // ---- inline dtype detection ----
  {
    const ushort_t* wu = (const ushort_t*)W1v;
    unsigned int u = wu[2 * t];
    int e = (u >> 7) & 0xff;
    cnt[t] = (e >= 90 && e <= 140) ? 1 : 0;
    __syncthreads();
    for (int ofs = 128; ofs > 0; ofs >>= 1) {
      if (t < ofs) cnt[t] += cnt[t + ofs];
      __syncthreads();
    }
    if (t == 0) isbf_sh = (cnt[0] >= 128) ? 1 : 0;
    __syncthreads();
  }
  const int isbf = isbf_sh;

  if (bid < 2048) {
    // ================= W2 transpose =================
    const int kt = bid & 127, nt = bid >> 7;
    const int r = t >> 3, c8 = (t & 7) * 8;
#pragma unroll
    for (int i = 0; i < 2; ++i) {
      int row = i * 32 + r;
      size_t base = (size_t)(kt * 64 + row) * BOTN + nt * 64 + c8;
      if (isbf) {
        u32x4 v = *(const u32x4*)((const ushort_t*)W2v + base);
        *(u32x4*)&tile[row][c8] = v;
      } else {
        const float* src = (const float*)W2v + base;
        float4 w0 = *(const float4*)src;
        float4 w1 = *(const float4*)(src + 4);
        u32x4 pk;
        pk.x = packbf(w0.x, w0.y);
        pk.y = packbf(w0.z, w0.w);
        pk.z = packbf(w1.x, w1.y);
        pk.w = packbf(w1.z, w1.w);
        *(u32x4*)&tile[row][c8] = pk;
      }
    }
    __syncthreads();
#pragma unroll
    for (int i = 0; i < 2; ++i) {
      int nrow = i * 32 + r;
      union { ushort_t us[8]; u32x4 v; } pk;
#pragma unroll
      for (int jj = 0; jj < 8; ++jj) pk.us[jj] = tile[c8 + jj][nrow];
      *(u32x4*)(W2T + (size_t)(nt * 64 + nrow) * D1 + kt * 64 + c8) = pk.v;
    }
  } else if (bid < 2304) {
    // ================= hc: hcb[j][k] = hbias[k] + h[j]@W1[64:] =============
    const int idx = bid - 2048;
    const int kb = idx & 7, jt = idx >> 3;
    const int kbase = kb * 1024 + t * 4;
    // ---- hbias inline: b1[k] + sum_e b_sp[e]*W1[e][k] ----
    float hb0, hb1, hb2, hb3;
    if (isbf) {
      const ushort_t* b1u = (const ushort_t*)b1v;
      const ushort_t* bspu = (const ushort_t*)b_spv;
      const ushort_t* wp = (const ushort_t*)W1v + kbase;
      hb0 = bf2f(b1u[kbase]); hb1 = bf2f(b1u[kbase + 1]);
      hb2 = bf2f(b1u[kbase + 2]); hb3 = bf2f(b1u[kbase + 3]);
      for (int e = 0; e < ED; ++e) {
        float bs = bf2f(bspu[e]);
        u32x2 wv = *(const u32x2*)(wp + (size_t)e * D1);
        float w0, w1, w2, w3;
        unpk(wv.x, w0, w1); unpk(wv.y, w2, w3);
        hb0 += bs * w0; hb1 += bs * w1; hb2 += bs * w2; hb3 += bs * w3;
      }
    } else {
      const float* b1f = (const float*)b1v;
      const float* bspf = (const float*)b_spv;
      const float* wp = (const float*)W1v + kbase;
      hb0 = b1f[kbase]; hb1 = b1f[kbase + 1];
      hb2 = b1f[kbase + 2]; hb3 = b1f[kbase + 3];
      for (int e = 0; e < ED; ++e) {
        float bs = bspf[e];
        float4 w = *(const float4*)(wp + (size_t)e * D1);
        hb0 += bs * w.x; hb1 += bs * w.y; hb2 += bs * w.z; hb3 += bs * w.w;
      }
    }
    // ---- main accumulation over h ----
    float acc[16][4];
#pragma unroll
    for (int j = 0; j < 16; ++j)
#pragma unroll
      for (int c = 0; c < 4; ++c) acc[j][c] = 0.f;
    if (isbf) {
      const ushort_t* wp = (const ushort_t*)W1v + (size_t)ED * D1 + kbase;
      const ushort_t* hp = (const ushort_t*)hv_ + jt * 16 * HD;
      for (int hh = 0; hh < HD; ++hh) {
        u32x2 wv = *(const u32x2*)(wp + (size_t)hh * D1);
        float w0, w1, w2, w3;
        unpk(wv.x, w0, w1); unpk(wv.y, w2, w3);
#pragma unroll
        for (int j = 0; j < 16; ++j) {
          float hj = bf2f(hp[j * HD + hh]);
          acc[j][0] += hj * w0;
          acc[j][1] += hj * w1;
          acc[j][2] += hj * w2;
          acc[j][3] += hj * w3;
        }
      }
    } else {
      const float* wp = (const float*)W1v + (size_t)ED * D1 + kbase;
      const float* hp = (const float*)hv_ + jt * 16 * HD;
#pragma unroll 4
      for (int hh = 0; hh < HD; ++hh) {
        float4 w = *(const float4*)(wp + (size_t)hh * D1);
#pragma unroll
        for (int j = 0; j < 16; ++j) {
          float hj = hp[j * HD + hh];
          acc[j][0] += hj * w.x;
          acc[j][1] += hj * w.y;
          acc[j][2] += hj * w.z;
          acc[j][3] += hj * w.w;
        }
      }
    }
#pragma unroll
    for (int j = 0; j < 16; ++j) {
      u32x2 pk;
      pk.x = packbf(acc[j][0] + hb0, acc[j][1] + hb1);
      pk.y = packbf(acc[j][2] + hb2, acc[j][3] + hb3);
      *(u32x2*)(hcb + (size_t)(jt * 16 + j) * D1 + kbase) = pk;
    }
  } else if (bid < 2336) {
    // ================= M0/M1 fold =================
    const int k = (bid - 2304) * 256 + t;
    float m0 = 0.f, m1 = 0.f;
    if (isbf) {
      const ushort_t* Wspu = (const ushort_t*)W_spv;
      const ushort_t* W1u = (const ushort_t*)W1v;
      for (int e = 0; e < ED; ++e) {
        float w = bf2f(W1u[e * D1 + k]);
        m0 += bf2f(Wspu[e]) * w;
        m1 += bf2f(Wspu[ED + e]) * w;
      }
    } else {
      const float* Wspf = (const float*)W_spv;
      const float* W1f = (const float*)W1v;
      for (int e = 0; e < ED; ++e) {
        float w = W1f[e * D1 + k];
        m0 += Wspf[e] * w;
        m1 += Wspf[ED + e] * w;
      }
    }
    M0[k] = m0;
    M1[k] = m1;
  } else {
    // ================= epf / b2f / flag =================
    if (t == 0) *flag = isbf;
    const ushort_t* epu = (const ushort_t*)end_posv;
    const float* epff = (const float*)end_posv;
    const ushort_t* b2u = (const ushort_t*)b2v;
    const float* b2ff = (const float*)b2v;
    for (int i = t; i < 1024; i += 256) {
      epf[i] = isbf ? bf2f(epu[i]) : epff[i];
      b2f[i] = isbf ? bf2f(b2u[i]) : b2ff[i];
    }
  }
}

// ---------------------------------------------------------------------------
// k_gemm (R6-proven, 336 us): fused A-gen + GEMM + max-pool epilogue.
// BM=64 BN=512 BK=64; grid 512: nb=bid&1, mb=bid>>1 (0..255).
// 4 waves, each 64m x 128n; 2 blocks/CU. B tile: DMA (global_load_lds w16)
// into unpadded [512][64] LDS, XOR swizzle applied on the GLOBAL fetch side.
// ---------------------------------------------------------------------------
#define ASTR 72  // A-tile LDS row stride in shorts (144B)
__global__ __launch_bounds__(256, 2) void k_gemm(
    const ushort_t* __restrict__ hcb, const float* __restrict__ M0f,
    const float* __restrict__ M1f, const ushort_t* __restrict__ W2T,
    const float* __restrict__ epf, const float* __restrict__ b2f,
    const int* __restrict__ flag, void* __restrict__ outv) {
  __shared__ ushort_t aLds[64 * ASTR];   // 9.2 KB, padded
  __shared__ ushort_t bLds[512 * 64];    // 64 KB, unpadded (DMA dest), swizzled
  __shared__ float2 rrLds[64];

  const int t = threadIdx.x;
  const int w = t >> 6;
  const int lane = t & 63;
  const int nb = blockIdx.x & 1;
  const int mb = blockIdx.x >> 1;  // 0..255
  const int s = mb >> 4;
  const int abase = (mb & 15) * 2;
  const int isbf = *flag;

  if (t < 64) {
    int g = t >> 5, b = t & 31;
    int pa = s * 32 + abase + g, pb = s * 32 + b;
    float r0 = epf[pb * 2] - epf[pa * 2];
    float r1 = epf[pb * 2 + 1] - epf[pa * 2 + 1];
    rrLds[t] = make_float2(clip1(r0), clip1(r1));
  }
  __syncthreads();

  const int bq = t >> 3;  // 0..31 : hc row (b) this thread generates
  const int kc = t & 7;   // 0..7  : 8-short chunk within BK
  float rr0[2], rr1[2];
#pragma unroll
  for (int g = 0; g < 2; ++g) {
    float2 v = rrLds[g * 32 + bq];
    rr0[g] = v.x;
    rr1[g] = v.y;
  }

  const ushort_t* hcRow = hcb + (size_t)(s * 32 + bq) * D1 + kc * 8;
  const float* m0p = M0f + kc * 8;
  const float* m1p = M1f + kc * 8;

  // B DMA addressing: lane covers row (i*32 + w*8 + (lane>>3)), LDS slot lane&7,
  // so it must FETCH global chunk (lane&7) ^ (lane>>3).
  const int rowl = w * 8 + (lane >> 3);
  const int chl = (lane & 7) ^ (lane >> 3);
  const ushort_t* bGlob = W2T + (size_t)(nb * 512 + rowl) * D1 + chl * 8;
  ushort_t* bLdsLane = bLds + (size_t)rowl * 64 + (lane & 7) * 8;  // base + lane*16B

  ushort_t* aW = aLds + bq * ASTR + kc * 8;  // + g*32*ASTR

  f32x4 acc[4][8];
#pragma unroll
  for (int mt = 0; mt < 4; ++mt)
#pragma unroll
    for (int nt = 0; nt < 8; ++nt) acc[mt][nt] = (f32x4){0.f, 0.f, 0.f, 0.f};

  const int rl = lane & 15, q = lane >> 4, r7 = rl & 7;
  const ushort_t* aRbase = aLds + rl * ASTR + q * 8;          // + mt*16*ASTR + ki*32
  const ushort_t* bRbase = bLds + (w * 128 + rl) * 64;        // + nt*1024 + slot*8
  const int sl0 = (q ^ r7) * 8;        // ki=0: global chunk q
  const int sl1 = ((q + 4) ^ r7) * 8;  // ki=1: global chunk q+4

  for (int kk = 0; kk < D1 / 64; ++kk) {
    const int k0 = kk * 64;
    // ---- B tile: async DMA global->LDS (16B/lane, 16 issues) ----
#pragma unroll
    for (int i = 0; i < 16; ++i)
      async_load16(bGlob + (size_t)i * 32 * D1 + k0, bLdsLane + i * 32 * 64);

    // ---- A-gen: relu(hc + r0*M0 + r1*M1), pack bf16, write LDS ----
    u32x4 hv = *(const u32x4*)(hcRow + k0);
    float h0, h1, h2, h3, h4, h5, h6, h7;
    unpk(hv.x, h0, h1); unpk(hv.y, h2, h3);
    unpk(hv.z, h4, h5); unpk(hv.w, h6, h7);
    float4 a0 = *(const float4*)(m0p + k0);
    float4 a1 = *(const float4*)(m0p + k0 + 4);
    float4 c0 = *(const float4*)(m1p + k0);
    float4 c1 = *(const float4*)(m1p + k0 + 4);
#pragma unroll
    for (int g = 0; g < 2; ++g) {
      float r0 = rr0[g], r1 = rr1[g];
      float v0 = fmaxf(h0 + r0 * a0.x + r1 * c0.x, 0.f);
      float v1 = fmaxf(h1 + r0 * a0.y + r1 * c0.y, 0.f);
      float v2 = fmaxf(h2 + r0 * a0.z + r1 * c0.z, 0.f);
      float v3 = fmaxf(h3 + r0 * a0.w + r1 * c0.w, 0.f);
      float v4 = fmaxf(h4 + r0 * a1.x + r1 * c1.x, 0.f);
      float v5 = fmaxf(h5 + r0 * a1.y + r1 * c1.y, 0.f);
      float v6 = fmaxf(h6 + r0 * a1.z + r1 * c1.z, 0.f);
      float v7 = fmaxf(h7 + r0 * a1.w + r1 * c1.w, 0.f);
      u32x4 pk;
      pk.x = packbf(v0, v1);
      pk.y = packbf(v2, v3);
      pk.z = packbf(v4, v5);
      pk.w = packbf(v6, v7);
      *(u32x4*)(aW + g * 32 * ASTR) = pk;
    }
    __syncthreads();  // drains DMA (vmcnt) + A-gen ds_writes

    // ---- mfma phase ----
#pragma unroll
    for (int ki = 0; ki < 2; ++ki) {
      bf16x8 af[4], bfr[8];
#pragma unroll
      for (int mt = 0; mt < 4; ++mt)
        af[mt] = *(const bf16x8*)(aRbase + mt * 16 * ASTR + ki * 32);
      const int slk = ki ? sl1 : sl0;
#pragma unroll
      for (int nt = 0; nt < 8; ++nt)
        bfr[nt] = *(const bf16x8*)(bRbase + nt * 1024 + slk);
#pragma unroll
      for (int mt = 0; mt < 4; ++mt)
#pragma unroll
        for (int nt = 0; nt < 8; ++nt)
          acc[mt][nt] = __builtin_amdgcn_mfma_f32_16x16x32_bf16(
              af[mt], bfr[nt], acc[mt][nt], 0, 0, 0);
    }
    __syncthreads();
  }

  // ---- epilogue: max over b (32 m-rows/group), +b2, relu, store ----
#pragma unroll
  for (int g = 0; g < 2; ++g) {
    int orow = s * 32 + abase + g;
#pragma unroll
    for (int nt = 0; nt < 8; ++nt) {
      f32x4 x0 = acc[2 * g][nt], x1 = acc[2 * g + 1][nt];
      float v = fmaxf(fmaxf(fmaxf(x0.x, x0.y), fmaxf(x0.z, x0.w)),
                      fmaxf(fmaxf(x1.x, x1.y), fmaxf(x1.z, x1.w)));
      v = fmaxf(v, __shfl_xor(v, 16, 64));
      v = fmaxf(v, __shfl_xor(v, 32, 64));
      if (lane < 16) {
        int col = nb * 512 + w * 128 + nt * 16 + lane;
        float o = fmaxf(v + b2f[col], 0.f);
        if (isbf)
          ((ushort_t*)outv)[(size_t)orow * BOTN + col] = f2bf(o);
        else
          ((float*)outv)[(size_t)orow * BOTN + col] = o;
      }
    }
  }
}

extern "C" void kernel_launch(void* const* d_in, const int* in_sizes, int n_in,
                              void* d_out, int out_size, void* d_ws, size_t ws_size,
                              hipStream_t stream) {
  (void)in_sizes; (void)n_in; (void)out_size; (void)ws_size;
  const void* h_states = d_in[0];
  const void* end_pos = d_in[1];
  // d_in[2] rel_pos: unused by reference; d_in[3] seq_start_end: fixed equal scenes
  const void* W_sp = d_in[4];
  const void* b_sp = d_in[5];
  const void* W1 = d_in[6];
  const void* b1 = d_in[7];
  const void* W2 = d_in[8];
  const void* b2 = d_in[9];

  char* ws = (char*)d_ws;
  ushort_t* hcb = (ushort_t*)ws;                         // 8 MB  (512x8192 bf16)
  ushort_t* W2T = (ushort_t*)(ws + (8u << 20));          // 16 MB (1024x8192 bf16)
  float* M0f = (float*)(ws + (24u << 20));               // 32 KB
  float* M1f = (float*)(ws + (24u << 20) + 32768);       // 32 KB
  float* epf = (float*)(ws + (24u << 20) + 98304);       // 4 KB
  float* b2f = (float*)(ws + (24u << 20) + 102400);      // 4 KB
  int* flag = (int*)(ws + (24u << 20) + 106496);         // 4 B

  k_pre<<<dim3(2337), dim3(256), 0, stream>>>(
      h_states, end_pos, W_sp, b_sp, W1, b1, W2, b2,
      flag, epf, b2f, M0f, M1f, hcb, W2T);
  k_gemm<<<dim3(512), dim3(256), 0, stream>>>(hcb, M0f, M1f, W2T, epf, b2f, flag, d_out);
}